// Round 2
// baseline (6742.786 us; speedup 1.0000x reference)
//
#include <hip/hip_runtime.h>

typedef _Float16 h2f __attribute__((ext_vector_type(2)));
typedef unsigned int u32;
typedef unsigned short u16;

#define B_ 128
#define S_ 1024
#define I_ 256
#define H_ 512
#define O_ 256
#define IH_ 768

#if __has_builtin(__builtin_amdgcn_fdot2)
__device__ __forceinline__ float fdot2u(u32 a, u32 b, float c) {
    return __builtin_amdgcn_fdot2(__builtin_bit_cast(h2f, a),
                                  __builtin_bit_cast(h2f, b), c, false);
}
#else
__device__ __forceinline__ float fdot2u(u32 a, u32 b, float c) {
    h2f av = __builtin_bit_cast(h2f, a), bv = __builtin_bit_cast(h2f, b);
    return c + (float)av.x * (float)bv.x + (float)av.y * (float)bv.y;
}
#endif

__device__ __forceinline__ u32 pack2(float x, float y) {
    return __builtin_bit_cast(u32, __builtin_amdgcn_cvt_pkrtz(x, y));
}

__device__ __forceinline__ float tanh_fast(float x) {
    float e = __expf(-2.f * fabsf(x));     // e in (0,1] -- no overflow path
    float r = (1.f - e) / (1.f + e);
    return copysignf(r, x);
}

// ---------------------------------------------------------------------------
// Kernel A: repack W_i2h (512 x 768 fp32, row-major) into f16 pair-dwords.
//   wh[j*256 + m] = (W[j][256+2m], W[j][256+2m+1])   (Wh, column-major pairs)
//   wx[j*128 + m] = (W[j][2m],     W[j][2m+1])       (Wx, column-major pairs)
// ---------------------------------------------------------------------------
__global__ __launch_bounds__(256) void k_convert(const float* __restrict__ W,
                                                 u32* __restrict__ wh,
                                                 u32* __restrict__ wx) {
    int tid = blockIdx.x * 256 + threadIdx.x;
    if (tid < 512 * 256) {
        int j = tid >> 8, m = tid & 255;
        const float* r = W + j * IH_ + I_ + 2 * m;
        wh[j * 256 + m] = pack2(r[0], r[1]);
    } else {
        int k = tid - 512 * 256;           // < 512*128
        int j = k >> 7, m = k & 127;
        const float* r = W + j * IH_ + 2 * m;
        wx[j * 128 + m] = pack2(r[0], r[1]);
    }
}

// ---------------------------------------------------------------------------
// Phase 1: pre[r][j] = b_i2h[j] + sum_i x[r][i]*Wx[i][j], stored f16.
// Grid 2048 = 1024 row-blocks x 2 col-halves, 256 threads = 256 columns.
// Wx column resident in 32 uint4 VGPRs (SROA-friendly size); x row broadcast
// via one float4 load + cvt_pkrtz + v_readlane.
// ---------------------------------------------------------------------------
__global__ __launch_bounds__(256, 2) void k_phase1(const float* __restrict__ seq,
                                                   const u32* __restrict__ wx,
                                                   const float* __restrict__ bias,
                                                   u16* __restrict__ pre) {
    int half = blockIdx.x & 1;
    int rb   = blockIdx.x >> 1;
    int j    = half * 256 + threadIdx.x;
    int lane = threadIdx.x & 63;
    uint4 w4[32];
    const uint4* wp = (const uint4*)(wx + j * 128);
#pragma unroll
    for (int m = 0; m < 32; ++m) w4[m] = wp[m];
    float bj = bias[j];
    int r0 = rb * 128;
    for (int rr = 0; rr < 128; ++rr) {
        int r = r0 + rr;
        const float4* xr = (const float4*)(seq + (long)r * I_);
        float4 xv = xr[lane];                    // lane l holds x[4l..4l+3]
        int s0 = (int)pack2(xv.x, xv.y);         // x-pair 2*l
        int s1 = (int)pack2(xv.z, xv.w);         // x-pair 2*l+1
        float a0 = bj, a1 = 0.f, a2 = 0.f, a3 = 0.f;
#pragma unroll
        for (int c = 0; c < 32; ++c) {           // pairs 4c..4c+3
            uint4 wv = w4[c];
            a0 = fdot2u((u32)__builtin_amdgcn_readlane(s0, 2 * c),     wv.x, a0);
            a1 = fdot2u((u32)__builtin_amdgcn_readlane(s1, 2 * c),     wv.y, a1);
            a2 = fdot2u((u32)__builtin_amdgcn_readlane(s0, 2 * c + 1), wv.z, a2);
            a3 = fdot2u((u32)__builtin_amdgcn_readlane(s1, 2 * c + 1), wv.w, a3);
        }
        float acc = (a0 + a1) + (a2 + a3);
        pre[(long)r * H_ + j] = __builtin_bit_cast(u16, (_Float16)acc);
    }
}

// ---------------------------------------------------------------------------
// Phase 2: persistent recurrence. One WG per batch row (128 WGs x 512 thr).
// Thread j owns hidden column j. Wh column: pair-dwords 0..191 register-
// resident as 3x16 uint4 (small arrays -> guaranteed SROA promotion),
// 192..255 streamed from L2 each step behind an asm LICM-barrier (hoisting
// those 16 uint4 would blow the 256-VGPR budget -> spill, R1's failure).
// h ping-pong in LDS as f16; one ds_read_b128/wave/step gathers all 256 h
// pair-dwords, v_readlane broadcasts. One __syncthreads per step.
// ---------------------------------------------------------------------------
__global__ __launch_bounds__(512, 2) void k_phase2(const u16* __restrict__ pre,
                                                   const u32* __restrict__ wh,
                                                   const float* __restrict__ Who,
                                                   const float* __restrict__ bo,
                                                   float* __restrict__ out) {
    __shared__ __align__(16) u16 hbuf[2][H_];
    int b = blockIdx.x;
    int j = threadIdx.x;
    int lane = j & 63;
    const u32* gw = wh + j * 256;
    uint4 wa[16], wb[16], wc[16];
    const uint4* gw4 = (const uint4*)gw;
#pragma unroll
    for (int m = 0; m < 16; ++m) wa[m] = gw4[m];
#pragma unroll
    for (int m = 0; m < 16; ++m) wb[m] = gw4[16 + m];
#pragma unroll
    for (int m = 0; m < 16; ++m) wc[m] = gw4[32 + m];
    unsigned long long wsa = (unsigned long long)(gw + 192);
    const u16* prow = pre + (long)b * S_ * H_;
    hbuf[0][j] = 0;                                // h0 = 0 (f16 +0.0)
    __syncthreads();
    u16 pv = prow[j];                              // pre for t=0
    for (int t = 0; t < S_; ++t) {
        int cur = t & 1, nxt = cur ^ 1;
        int tn = (t + 1 < S_) ? (t + 1) : t;
        u16 pnext = prow[(long)tn * H_ + j];       // prefetch next step's pre
        asm volatile("" : "+v"(wsa));              // block LICM of streamed loads
        const uint4* wst = (const uint4*)wsa;
        uint4 hv = ((const uint4*)hbuf[cur])[lane]; // lane l: h pairs 4l..4l+3
        float a0 = (float)__builtin_bit_cast(_Float16, pv);
        float a1 = 0.f, a2 = 0.f, a3 = 0.f;
#pragma unroll
        for (int c = 0; c < 16; ++c) {             // pairs 4c..4c+3, lanes 0..15
            uint4 wv = wa[c];
            a0 = fdot2u((u32)__builtin_amdgcn_readlane((int)hv.x, c), wv.x, a0);
            a1 = fdot2u((u32)__builtin_amdgcn_readlane((int)hv.y, c), wv.y, a1);
            a2 = fdot2u((u32)__builtin_amdgcn_readlane((int)hv.z, c), wv.z, a2);
            a3 = fdot2u((u32)__builtin_amdgcn_readlane((int)hv.w, c), wv.w, a3);
        }
#pragma unroll
        for (int c = 16; c < 32; ++c) {            // lanes 16..31
            uint4 wv = wb[c - 16];
            a0 = fdot2u((u32)__builtin_amdgcn_readlane((int)hv.x, c), wv.x, a0);
            a1 = fdot2u((u32)__builtin_amdgcn_readlane((int)hv.y, c), wv.y, a1);
            a2 = fdot2u((u32)__builtin_amdgcn_readlane((int)hv.z, c), wv.z, a2);
            a3 = fdot2u((u32)__builtin_amdgcn_readlane((int)hv.w, c), wv.w, a3);
        }
#pragma unroll
        for (int c = 32; c < 48; ++c) {            // lanes 32..47
            uint4 wv = wc[c - 32];
            a0 = fdot2u((u32)__builtin_amdgcn_readlane((int)hv.x, c), wv.x, a0);
            a1 = fdot2u((u32)__builtin_amdgcn_readlane((int)hv.y, c), wv.y, a1);
            a2 = fdot2u((u32)__builtin_amdgcn_readlane((int)hv.z, c), wv.z, a2);
            a3 = fdot2u((u32)__builtin_amdgcn_readlane((int)hv.w, c), wv.w, a3);
        }
#pragma unroll
        for (int c = 48; c < 64; ++c) {            // lanes 48..63, L2-streamed
            uint4 sw = wst[c - 48];
            a0 = fdot2u((u32)__builtin_amdgcn_readlane((int)hv.x, c), sw.x, a0);
            a1 = fdot2u((u32)__builtin_amdgcn_readlane((int)hv.y, c), sw.y, a1);
            a2 = fdot2u((u32)__builtin_amdgcn_readlane((int)hv.z, c), sw.z, a2);
            a3 = fdot2u((u32)__builtin_amdgcn_readlane((int)hv.w, c), sw.w, a3);
        }
        float acc = (a0 + a1) + (a2 + a3);
        float r = tanh_fast(acc);
        hbuf[nxt][j] = __builtin_bit_cast(u16, (_Float16)r);
        pv = pnext;
        __syncthreads();
    }
    // final h lives in hbuf[0] (last write: t=1023 -> nxt=0)
    float hj = (float)__builtin_bit_cast(_Float16, hbuf[0][j]);
    out[(long)B_ * O_ + (long)b * H_ + j] = hj;    // hidden output
    if (j < O_) {                                  // o = h @ W_h2o^T + b_h2o
        float acc = bo[j];
        const float4* wr = (const float4*)(Who + (long)j * H_);
        const u16* hb = hbuf[0];
#pragma unroll 4
        for (int k = 0; k < 128; ++k) {
            float4 wv = wr[k];
            acc += (float)__builtin_bit_cast(_Float16, hb[4 * k + 0]) * wv.x
                 + (float)__builtin_bit_cast(_Float16, hb[4 * k + 1]) * wv.y
                 + (float)__builtin_bit_cast(_Float16, hb[4 * k + 2]) * wv.z
                 + (float)__builtin_bit_cast(_Float16, hb[4 * k + 3]) * wv.w;
        }
        out[(long)b * O_ + j] = acc;
    }
}

// ---------------------------------------------------------------------------
// Fallback (workspace too small): straightforward fp32, correct but slow.
// ---------------------------------------------------------------------------
__global__ __launch_bounds__(512) void k_fallback(const float* __restrict__ seq,
                                                  const float* __restrict__ W,
                                                  const float* __restrict__ bias,
                                                  const float* __restrict__ Who,
                                                  const float* __restrict__ bo,
                                                  float* __restrict__ out) {
    __shared__ float hb[2][H_];
    int b = blockIdx.x, j = threadIdx.x;
    const float* wrow = W + (long)j * IH_;
    float bj = bias[j];
    hb[0][j] = 0.f;
    __syncthreads();
    for (int t = 0; t < S_; ++t) {
        const float* x = seq + ((long)b * S_ + t) * I_;
        float acc = bj;
        for (int i = 0; i < I_; ++i) acc += x[i] * wrow[i];
        const float* hc = hb[t & 1];
        for (int k = 0; k < H_; ++k) acc += hc[k] * wrow[I_ + k];
        hb[(t & 1) ^ 1][j] = tanh_fast(acc);
        __syncthreads();
    }
    float hj = hb[0][j];
    out[(long)B_ * O_ + (long)b * H_ + j] = hj;
    if (j < O_) {
        float acc = bo[j];
        const float* wr = Who + (long)j * H_;
        for (int k = 0; k < H_; ++k) acc += hb[0][k] * wr[k];
        out[(long)b * O_ + j] = acc;
    }
}

extern "C" void kernel_launch(void* const* d_in, const int* in_sizes, int n_in,
                              void* d_out, int out_size, void* d_ws, size_t ws_size,
                              hipStream_t stream) {
    const float* seq = (const float*)d_in[0];   // (128,1024,256) fp32
    const float* W   = (const float*)d_in[1];   // (512,768) fp32
    const float* bi  = (const float*)d_in[2];   // (512,)
    const float* Who = (const float*)d_in[3];   // (256,512)
    const float* bo  = (const float*)d_in[4];   // (256,)
    float* out = (float*)d_out;                 // 32768 output + 65536 hidden

    const size_t PRE_OFF = 1u << 20;                              // 1 MB for packed weights
    const size_t WS_NEED = PRE_OFF + (size_t)B_ * S_ * H_ * 2;    // + 128 MB f16 pre

    if (ws_size >= WS_NEED) {
        u32* wh  = (u32*)d_ws;                  // 512*256 dwords = 512 KB
        u32* wx  = wh + 512 * 256;              // 512*128 dwords = 256 KB
        u16* pre = (u16*)((char*)d_ws + PRE_OFF);
        k_convert<<<768, 256, 0, stream>>>(W, wh, wx);
        k_phase1<<<2048, 256, 0, stream>>>(seq, wx, bi, pre);
        k_phase2<<<B_, 512, 0, stream>>>(pre, wh, Who, bo, out);
    } else {
        k_fallback<<<B_, 512, 0, stream>>>(seq, W, bi, Who, bo, out);
    }
}

// Round 3
// 3175.358 us; speedup vs baseline: 2.1235x; 2.1235x over previous
//
#include <hip/hip_runtime.h>

typedef _Float16 h2f __attribute__((ext_vector_type(2)));
typedef unsigned int u32;
typedef unsigned short u16;

#define B_ 128
#define S_ 1024
#define I_ 256
#define H_ 512
#define O_ 256
#define IH_ 768

#if __has_builtin(__builtin_amdgcn_fdot2)
__device__ __forceinline__ float fdot2u(u32 a, u32 b, float c) {
    return __builtin_amdgcn_fdot2(__builtin_bit_cast(h2f, a),
                                  __builtin_bit_cast(h2f, b), c, false);
}
#else
__device__ __forceinline__ float fdot2u(u32 a, u32 b, float c) {
    h2f av = __builtin_bit_cast(h2f, a), bv = __builtin_bit_cast(h2f, b);
    return c + (float)av.x * (float)bv.x + (float)av.y * (float)bv.y;
}
#endif

__device__ __forceinline__ u32 pack2(float x, float y) {
    return __builtin_bit_cast(u32, __builtin_amdgcn_cvt_pkrtz(x, y));
}

__device__ __forceinline__ float tanh_fast(float x) {
    float e = __expf(-2.f * fabsf(x));     // e in (0,1] -- no overflow path
    float r = (1.f - e) / (1.f + e);
    return copysignf(r, x);
}

// ---- repetition macros (named SSA values; NO arrays -> no SROA gamble) ----
#define REPR_A(X) X(0) X(1) X(2) X(3) X(4) X(5) X(6) X(7) X(8) X(9) \
                  X(10) X(11) X(12) X(13) X(14) X(15) X(16) X(17) X(18) X(19)
#define REPR_B(X) X(20) X(21) X(22) X(23) X(24) X(25) X(26) X(27) X(28) X(29) \
                  X(30) X(31) X(32) X(33) X(34) X(35) X(36) X(37) X(38) X(39)
#define REP40(X) REPR_A(X) REPR_B(X)
#define REP32(X) X(0) X(1) X(2) X(3) X(4) X(5) X(6) X(7) X(8) X(9) \
                 X(10) X(11) X(12) X(13) X(14) X(15) X(16) X(17) X(18) X(19) \
                 X(20) X(21) X(22) X(23) X(24) X(25) X(26) X(27) X(28) X(29) \
                 X(30) X(31)
#define REPS0(X) X(0) X(1) X(2) X(3) X(4) X(5) X(6) X(7)
#define REPS1(X) X(8) X(9) X(10) X(11) X(12) X(13) X(14) X(15)
#define REPS2(X) X(16) X(17) X(18) X(19) X(20) X(21) X(22) X(23)
#define REPL0(X) X(0) X(1) X(2) X(3)
#define REPL1(X) X(4) X(5) X(6) X(7)
#define REPL2(X) X(8) X(9) X(10) X(11)
#define REPL3(X) X(12) X(13) X(14) X(15)

// ---------------------------------------------------------------------------
// Workspace layout (dwords from d_ws):
//   whr @ 0      : 512*160  resident Wh pairs, [col][pair 0..159]
//   whl @ 81920  : 8 slabs  [slab][col] uint4 = pairs 160+4s..+3 (L2-streamed)
//   whs @ 98304  : 16 slabs [slab][col] uint4 = pairs 192+4s..+3 (LDS-resident)
//   wx  @ 131072 : 512*128  Wx pairs, [col][pair 0..127]
//   pre @ 1 MB   : 128*1024*512 f16 pre-activations
// whl and whs are adjacent -> fallback variant streams all 24 slabs from whl.
// ---------------------------------------------------------------------------
__global__ __launch_bounds__(256) void k_convert(const float* __restrict__ W,
                                                 u32* __restrict__ whr,
                                                 u32* __restrict__ whl,
                                                 u32* __restrict__ whs,
                                                 u32* __restrict__ wx) {
    int tid = blockIdx.x * 256 + threadIdx.x;
    if (tid < 512 * 256) {
        int j = tid >> 8, m = tid & 255;
        const float* r = W + j * IH_ + I_ + 2 * m;
        u32 v = pack2(r[0], r[1]);
        if (m < 160) {
            whr[j * 160 + m] = v;
        } else if (m < 192) {
            int k = (m - 160) >> 2, c = m & 3;
            whl[(k * 512 + j) * 4 + c] = v;
        } else {
            int s = (m - 192) >> 2, c = m & 3;
            whs[(s * 512 + j) * 4 + c] = v;
        }
    } else {
        int t = tid - 512 * 256;           // < 512*128
        int j = t >> 7, m = t & 127;
        const float* r = W + j * IH_ + 2 * m;
        wx[j * 128 + m] = pack2(r[0], r[1]);
    }
}

// ---------------------------------------------------------------------------
// Phase 1: pre[r][j] = b_i2h[j] + sum_i x[r][i]*Wx[i][j], stored f16.
// Grid 2048 = 1024 row-blocks x 2 col-halves, 256 threads = 256 columns.
// Wx column in 32 NAMED uint4 VGPRs; x row broadcast via float4 load +
// cvt_pkrtz + v_readlane.
// ---------------------------------------------------------------------------
__global__ __launch_bounds__(256, 2) void k_phase1(const float* __restrict__ seq,
                                                   const u32* __restrict__ wx,
                                                   const float* __restrict__ bias,
                                                   u16* __restrict__ pre) {
    int half = blockIdx.x & 1;
    int rb   = blockIdx.x >> 1;
    int j    = half * 256 + threadIdx.x;
    int lane = threadIdx.x & 63;
    const uint4* wxq = (const uint4*)wx + j * 32;
#define DECLX(i) uint4 x##i = wxq[i];
    REP32(DECLX)
#undef DECLX
    float bj = bias[j];
    int r0 = rb * 128;
    for (int rr = 0; rr < 128; ++rr) {
        int r = r0 + rr;
        const float4* xr = (const float4*)(seq + (long)r * I_);
        float4 xv = xr[lane];                    // lane l holds x[4l..4l+3]
        int xs0 = (int)pack2(xv.x, xv.y);        // x-pair 2*l
        int xs1 = (int)pack2(xv.z, xv.w);        // x-pair 2*l+1
        float a0 = bj, a1 = 0.f, a2 = 0.f, a3 = 0.f;
#define P1DOT(i) \
        a0 = fdot2u((u32)__builtin_amdgcn_readlane(xs0, 2*(i)),   x##i.x, a0); \
        a1 = fdot2u((u32)__builtin_amdgcn_readlane(xs1, 2*(i)),   x##i.y, a1); \
        a2 = fdot2u((u32)__builtin_amdgcn_readlane(xs0, 2*(i)+1), x##i.z, a2); \
        a3 = fdot2u((u32)__builtin_amdgcn_readlane(xs1, 2*(i)+1), x##i.w, a3);
        REP32(P1DOT)
#undef P1DOT
        float acc = (a0 + a1) + (a2 + a3);
        pre[(long)r * H_ + j] = __builtin_bit_cast(u16, (_Float16)acc);
    }
}

// ---------------------------------------------------------------------------
// Phase 2: persistent recurrence, one WG per batch row (128 WGs x 512 thr).
// Thread j owns hidden column j (64 pair-dword uint4s of Wh):
//   - 40 in NAMED VGPRs (loaded once; named SSA -> guaranteed registers)
//   - NLDS slabs LDS-resident (filled once; ds_read_b128 per step, [slab][col]
//     layout -> conflict-free, separate LDS pipe overlaps VALU)
//   - NL2 slabs streamed from L2 per step ([slab][col] -> coalesced)
// h ping-pong in LDS f16; 1 ds_read_b128/lane/step + v_readlane broadcast.
// zoff/lz asm-barriers stop LICM from hoisting streamed loads (the +64-reg
// hoist is what triggered wholesale spilling in R1/R2).
// ---------------------------------------------------------------------------
template<int NL2, int NLDS>
__global__ __launch_bounds__(512, 2) void k_phase2(const u16* __restrict__ pre,
                                                   const u32* __restrict__ whr,
                                                   const uint4* __restrict__ whl4,
                                                   const float* __restrict__ Who,
                                                   const float* __restrict__ bo,
                                                   float* __restrict__ out) {
    extern __shared__ uint4 wlds[];                // NLDS*512 uint4
    __shared__ __align__(16) u16 hbuf[2][H_];
    int b = blockIdx.x;
    int j = threadIdx.x;
    int lane = j & 63;
    const uint4* whr4 = (const uint4*)whr + j * 40;
#define DECLW(i) uint4 w##i = whr4[i];
    REP40(DECLW)
#undef DECLW
    if (NLDS > 0) {
#pragma unroll
        for (int s = 0; s < NLDS; ++s)
            wlds[s * 512 + j] = whl4[(NL2 + s) * 512 + j];
    }
    const u16* prow = pre + (long)b * S_ * H_;
    hbuf[0][j] = 0;                                // h0 = 0 (f16 +0.0)
    __syncthreads();
    u16 pv = prow[j];                              // pre for t=0
    for (int t = 0; t < S_; ++t) {
        int cur = t & 1, nxt = cur ^ 1;
        int tn = (t + 1 < S_) ? (t + 1) : t;
        int zoff = 0, lz = 0;
        asm volatile("" : "+v"(zoff), "+v"(lz));   // block LICM of weight loads
        u16 pnext = prow[(long)tn * H_ + j];       // prefetch next step's pre
        uint4 hv = ((const uint4*)hbuf[cur])[lane]; // lane l: h pairs 4l..4l+3
        float a0 = (float)__builtin_bit_cast(_Float16, pv);
        float a1 = 0.f, a2 = 0.f, a3 = 0.f;
#define SLOAD(i) uint4 s##i = whl4[(i) * 512 + j + zoff];
#define SDOT(i) \
        a0 = fdot2u((u32)__builtin_amdgcn_readlane((int)hv.x, 40 + (i)), s##i.x, a0); \
        a1 = fdot2u((u32)__builtin_amdgcn_readlane((int)hv.y, 40 + (i)), s##i.y, a1); \
        a2 = fdot2u((u32)__builtin_amdgcn_readlane((int)hv.z, 40 + (i)), s##i.z, a2); \
        a3 = fdot2u((u32)__builtin_amdgcn_readlane((int)hv.w, 40 + (i)), s##i.w, a3);
#define DOTR(i) \
        a0 = fdot2u((u32)__builtin_amdgcn_readlane((int)hv.x, (i)), w##i.x, a0); \
        a1 = fdot2u((u32)__builtin_amdgcn_readlane((int)hv.y, (i)), w##i.y, a1); \
        a2 = fdot2u((u32)__builtin_amdgcn_readlane((int)hv.z, (i)), w##i.z, a2); \
        a3 = fdot2u((u32)__builtin_amdgcn_readlane((int)hv.w, (i)), w##i.w, a3);
#define LLOAD(i) uint4 t##i = wlds[(i) * 512 + j + lz];
#define LDOT(i) \
        a0 = fdot2u((u32)__builtin_amdgcn_readlane((int)hv.x, 40 + NL2 + (i)), t##i.x, a0); \
        a1 = fdot2u((u32)__builtin_amdgcn_readlane((int)hv.y, 40 + NL2 + (i)), t##i.y, a1); \
        a2 = fdot2u((u32)__builtin_amdgcn_readlane((int)hv.z, 40 + NL2 + (i)), t##i.z, a2); \
        a3 = fdot2u((u32)__builtin_amdgcn_readlane((int)hv.w, 40 + NL2 + (i)), t##i.w, a3);
        if constexpr (NL2 == 8) {
            // A: 8 L2 slabs in flight across resident block; 16 LDS slabs
            REPS0(SLOAD)
            REPR_A(DOTR) REPR_B(DOTR)
            REPS0(SDOT)
            REPL0(LLOAD) REPL0(LDOT)
            REPL1(LLOAD) REPL1(LDOT)
            REPL2(LLOAD) REPL2(LDOT)
            REPL3(LLOAD) REPL3(LDOT)
        } else {
            // B (no big-LDS): 24 L2 slabs, 3 chunks of 8 to cap regs in flight
            REPS0(SLOAD)
            REPR_A(DOTR)
            REPS0(SDOT)
            REPS1(SLOAD)
            REPR_B(DOTR)
            REPS1(SDOT)
            REPS2(SLOAD)
            REPS2(SDOT)
        }
#undef SLOAD
#undef SDOT
#undef DOTR
#undef LLOAD
#undef LDOT
        float acc = (a0 + a1) + (a2 + a3);
        float r = tanh_fast(acc);
        hbuf[nxt][j] = __builtin_bit_cast(u16, (_Float16)r);
        pv = pnext;
        __syncthreads();
    }
    // final h lives in hbuf[0] (last write: t=1023 -> nxt=0)
    float hj = (float)__builtin_bit_cast(_Float16, hbuf[0][j]);
    out[(long)B_ * O_ + (long)b * H_ + j] = hj;    // hidden output
    if (j < O_) {                                  // o = h @ W_h2o^T + b_h2o
        float acc = bo[j];
        const float4* wr = (const float4*)(Who + (long)j * H_);
        const u16* hb = hbuf[0];
#pragma unroll 4
        for (int k = 0; k < 128; ++k) {
            float4 wv = wr[k];
            acc += (float)__builtin_bit_cast(_Float16, hb[4 * k + 0]) * wv.x
                 + (float)__builtin_bit_cast(_Float16, hb[4 * k + 1]) * wv.y
                 + (float)__builtin_bit_cast(_Float16, hb[4 * k + 2]) * wv.z
                 + (float)__builtin_bit_cast(_Float16, hb[4 * k + 3]) * wv.w;
        }
        out[(long)b * O_ + j] = acc;
    }
}

// ---------------------------------------------------------------------------
// Fallback (workspace too small): straightforward fp32, correct but slow.
// ---------------------------------------------------------------------------
__global__ __launch_bounds__(512) void k_fallback(const float* __restrict__ seq,
                                                  const float* __restrict__ W,
                                                  const float* __restrict__ bias,
                                                  const float* __restrict__ Who,
                                                  const float* __restrict__ bo,
                                                  float* __restrict__ out) {
    __shared__ float hb[2][H_];
    int b = blockIdx.x, j = threadIdx.x;
    const float* wrow = W + (long)j * IH_;
    float bj = bias[j];
    hb[0][j] = 0.f;
    __syncthreads();
    for (int t = 0; t < S_; ++t) {
        const float* x = seq + ((long)b * S_ + t) * I_;
        float acc = bj;
        for (int i = 0; i < I_; ++i) acc += x[i] * wrow[i];
        const float* hc = hb[t & 1];
        for (int k = 0; k < H_; ++k) acc += hc[k] * wrow[I_ + k];
        hb[(t & 1) ^ 1][j] = tanh_fast(acc);
        __syncthreads();
    }
    float hj = hb[0][j];
    out[(long)B_ * O_ + (long)b * H_ + j] = hj;
    if (j < O_) {
        float acc = bo[j];
        const float* wr = Who + (long)j * H_;
        for (int k = 0; k < H_; ++k) acc += hb[0][k] * wr[k];
        out[(long)b * O_ + j] = acc;
    }
}

extern "C" void kernel_launch(void* const* d_in, const int* in_sizes, int n_in,
                              void* d_out, int out_size, void* d_ws, size_t ws_size,
                              hipStream_t stream) {
    const float* seq = (const float*)d_in[0];   // (128,1024,256) fp32
    const float* W   = (const float*)d_in[1];   // (512,768) fp32
    const float* bi  = (const float*)d_in[2];   // (512,)
    const float* Who = (const float*)d_in[3];   // (256,512)
    const float* bo  = (const float*)d_in[4];   // (256,)
    float* out = (float*)d_out;                 // 32768 output + 65536 hidden

    const size_t PRE_OFF = 1u << 20;                              // 1 MB packed weights
    const size_t WS_NEED = PRE_OFF + (size_t)B_ * S_ * H_ * 2;    // + 128 MB f16 pre

    if (ws_size >= WS_NEED) {
        u32* wsd = (u32*)d_ws;
        u32* whr = wsd;                          // 512*160 dw
        u32* whl = wsd + 81920;                  // 8 slabs  (16384 dw)
        u32* whs = wsd + 98304;                  // 16 slabs (32768 dw)
        u32* wx  = wsd + 131072;                 // 512*128 dw
        u16* pre = (u16*)((char*)d_ws + PRE_OFF);
        k_convert<<<768, 256, 0, stream>>>(W, whr, whl, whs, wx);
        k_phase1<<<2048, 256, 0, stream>>>(seq, wx, bi, pre);
        // Variant A needs 128 KB dynamic LDS; enable if the runtime allows.
        hipError_t e = hipFuncSetAttribute(
            reinterpret_cast<const void*>(&k_phase2<8, 16>),
            hipFuncAttributeMaxDynamicSharedMemorySize, 16 * 512 * 16);
        if (e == hipSuccess) {
            k_phase2<8, 16><<<B_, 512, 16 * 512 * 16, stream>>>(
                pre, whr, (const uint4*)whl, Who, bo, out);
        } else {
            (void)hipGetLastError();             // clear sticky error
            k_phase2<24, 0><<<B_, 512, 0, stream>>>(
                pre, whr, (const uint4*)whl, Who, bo, out);
        }
    } else {
        k_fallback<<<B_, 512, 0, stream>>>(seq, W, bi, Who, bo, out);
    }
}